// Round 1
// baseline (3765.827 us; speedup 1.0000x reference)
//
#include <hip/hip_runtime.h>
#include <cstdint>

#define NB 16384   // batch
#define NM 256     // M
#define NN 1024    // N
#define NITER 16
#define TOPK 50
#define BMROW 32               // batch rows per block
#define NBLKS (NB / BMROW)     // 512 blocks

typedef __attribute__((ext_vector_type(8))) short short8;   // 8 bf16 = 4 VGPRs
typedef __attribute__((ext_vector_type(4))) float f32x4;

__device__ inline unsigned short f2bf(float x) {            // RNE fp32 -> bf16
    unsigned u = __float_as_uint(x);
    return (unsigned short)((u + 0x7FFFu + ((u >> 16) & 1u)) >> 16);
}
__device__ inline float bf2f(unsigned short h) {
    return __uint_as_float(((unsigned)h) << 16);
}

// ------------- precompute: element-wise split of phi (NM x NN) -------------
__global__ __launch_bounds__(256) void split_phi_kernel(const float* __restrict__ phi,
                                                        unsigned short* __restrict__ h,
                                                        unsigned short* __restrict__ l) {
    int i = blockIdx.x * 256 + threadIdx.x;
    float v = phi[i];
    unsigned short hh = f2bf(v);
    h[i] = hh;
    l[i] = f2bf(v - bf2f(hh));
}

// -------- precompute: W (NM x NN) -> Wt (NN x NM) transposed + split -------
__global__ __launch_bounds__(256) void transpose_split_W(const float* __restrict__ W,
                                                         unsigned short* __restrict__ th,
                                                         unsigned short* __restrict__ tl) {
    __shared__ float tile[32][33];
    int n0 = blockIdx.x * 32;
    int m0 = blockIdx.y * 32;
    int tx = threadIdx.x;   // 0..31
    int ty = threadIdx.y;   // 0..7
    #pragma unroll
    for (int i = 0; i < 32; i += 8)
        tile[ty + i][tx] = W[(size_t)(m0 + ty + i) * NN + n0 + tx];
    __syncthreads();
    #pragma unroll
    for (int i = 0; i < 32; i += 8) {
        float v = tile[tx][ty + i];
        unsigned short hh = f2bf(v);
        size_t idx = (size_t)(n0 + ty + i) * NM + m0 + tx;
        th[idx] = hh;
        tl[idx] = f2bf(v - bf2f(hh));
    }
}

// ---------------- fully fused persistent-iteration kernel ----------------
// One block = 32 batch rows for all 16 iterations. X never touches HBM.
// LDS (163840 B total, dynamic):
//   XH [32][1024] bf16 @ 0       row stride 2048B, within-row byte ^= ((row&7)<<4)
//   XL            @ 65536
//   RH [32][256]  bf16 @ 131072  row stride 512B, same swizzle   } reused as select
//   RL            @ 147456                                        } scratch after gemm2
#define XH_OFF 0
#define XL_OFF 65536
#define RH_OFF 131072
#define RL_OFF 147456
#define HSTRIDE 132                      // words per row: 256 bins packed 2/word + pad
#define PREF_OFF (131072 + 4224 * 4)     // u32[32] running prefix of threshold bits
#define RK_OFF (PREF_OFF + 128)          // u32[32] remaining rank

__global__ __launch_bounds__(512, 2) void alista_fused(
        const unsigned short* __restrict__ Ph, const unsigned short* __restrict__ Pl,
        const unsigned short* __restrict__ Wth, const unsigned short* __restrict__ Wtl,
        const float* __restrict__ y, const float* __restrict__ gamma,
        const float* __restrict__ theta, float* __restrict__ out) {
    extern __shared__ char lds[];
    const int tid = threadIdx.x;
    const int w = tid >> 6;          // wave 0..7
    const int lane = tid & 63;
    const int qd = lane >> 4;        // quad 0..3
    const int r16 = lane & 15;
    const int gb0 = blockIdx.x * BMROW;
    const unsigned swzA = (unsigned)((r16 & 7) << 4);   // A-frag row swizzle

    // zero X (XH+XL = 131072 B)
    {
        uint32_t* p = (uint32_t*)lds;
        #pragma unroll
        for (int i = 0; i < 64; ++i) p[tid + i * 512] = 0u;
    }
    __syncthreads();

    // gemm1 B (phi rows m = w*32 + {0,16} + r16), 16B per lane per k-step
    const unsigned short* pPh0 = Ph + (size_t)(w * 32 + r16) * NN + qd * 8;
    const unsigned short* pPh1 = pPh0 + 16 * NN;
    const unsigned short* pPl0 = Pl + (size_t)(w * 32 + r16) * NN + qd * 8;
    const unsigned short* pPl1 = pPl0 + 16 * NN;
    // gemm2 B (Wt rows n = w*128 + j*16 + r16)
    const size_t wn0 = (size_t)(w * 128 + r16) * NM + qd * 8;

    for (int it = 0; it < NITER; ++it) {
        const float gm = gamma[it];
        const float thv = theta[it];

        // ---- GEMM1: Rt[b,m] = sum_n X[b,n]*phi[m,n] - y[b,m]  (K = 1024) ----
        f32x4 acc1[2][2];
        #pragma unroll
        for (int i = 0; i < 2; ++i)
            #pragma unroll
            for (int j = 0; j < 2; ++j) acc1[i][j] = (f32x4){0.f, 0.f, 0.f, 0.f};

        #pragma unroll 4
        for (int k = 0; k < 32; ++k) {
            short8 bh[2], bl[2], ah[2], al[2];
            bh[0] = *(const short8*)(pPh0 + k * 32);
            bh[1] = *(const short8*)(pPh1 + k * 32);
            bl[0] = *(const short8*)(pPl0 + k * 32);
            bl[1] = *(const short8*)(pPl1 + k * 32);
            const unsigned mo = ((unsigned)(k * 64 + qd * 16)) ^ swzA;
            ah[0] = *(const short8*)(lds + XH_OFF + r16 * 2048 + mo);
            ah[1] = *(const short8*)(lds + XH_OFF + (r16 + 16) * 2048 + mo);
            al[0] = *(const short8*)(lds + XL_OFF + r16 * 2048 + mo);
            al[1] = *(const short8*)(lds + XL_OFF + (r16 + 16) * 2048 + mo);
            #pragma unroll
            for (int bb = 0; bb < 2; ++bb)
                #pragma unroll
                for (int m = 0; m < 2; ++m) {
                    acc1[bb][m] = __builtin_amdgcn_mfma_f32_16x16x32_bf16(ah[bb], bh[m], acc1[bb][m], 0, 0, 0);
                    acc1[bb][m] = __builtin_amdgcn_mfma_f32_16x16x32_bf16(ah[bb], bl[m], acc1[bb][m], 0, 0, 0);
                    acc1[bb][m] = __builtin_amdgcn_mfma_f32_16x16x32_bf16(al[bb], bh[m], acc1[bb][m], 0, 0, 0);
                }
        }
        // epilogue: -y, split bf16 hi/lo, store Rt to LDS
        #pragma unroll
        for (int bb = 0; bb < 2; ++bb)
            #pragma unroll
            for (int m = 0; m < 2; ++m) {
                const int gmn = w * 32 + m * 16 + r16;
                #pragma unroll
                for (int r = 0; r < 4; ++r) {
                    const int b = bb * 16 + qd * 4 + r;
                    float v = acc1[bb][m][r] - y[(size_t)(gb0 + b) * NM + gmn];
                    unsigned short h = f2bf(v);
                    const unsigned mb = ((unsigned)(gmn * 2)) ^ ((unsigned)((b & 7) << 4));
                    *(unsigned short*)(lds + RH_OFF + b * 512 + mb) = h;
                    *(unsigned short*)(lds + RL_OFF + b * 512 + mb) = f2bf(v - bf2f(h));
                }
            }
        __syncthreads();   // Rt visible to all waves

        // ---- GEMM2: acc2[b,n] = sum_m Rt[b,m]*W[m,n]  (K = 256) ----
        f32x4 acc2[2][8];
        #pragma unroll
        for (int i = 0; i < 2; ++i)
            #pragma unroll
            for (int j = 0; j < 8; ++j) acc2[i][j] = (f32x4){0.f, 0.f, 0.f, 0.f};

        #pragma unroll 2
        for (int k = 0; k < 8; ++k) {
            short8 wh[8], wl[8];
            #pragma unroll
            for (int j = 0; j < 8; ++j) {
                wh[j] = *(const short8*)(Wth + wn0 + j * 4096 + k * 32);
                wl[j] = *(const short8*)(Wtl + wn0 + j * 4096 + k * 32);
            }
            const unsigned mo = ((unsigned)(k * 64 + qd * 16)) ^ swzA;
            short8 ah[2], al[2];
            ah[0] = *(const short8*)(lds + RH_OFF + r16 * 512 + mo);
            ah[1] = *(const short8*)(lds + RH_OFF + (r16 + 16) * 512 + mo);
            al[0] = *(const short8*)(lds + RL_OFF + r16 * 512 + mo);
            al[1] = *(const short8*)(lds + RL_OFF + (r16 + 16) * 512 + mo);
            #pragma unroll
            for (int bb = 0; bb < 2; ++bb)
                #pragma unroll
                for (int j = 0; j < 8; ++j) {
                    acc2[bb][j] = __builtin_amdgcn_mfma_f32_16x16x32_bf16(ah[bb], wh[j], acc2[bb][j], 0, 0, 0);
                    acc2[bb][j] = __builtin_amdgcn_mfma_f32_16x16x32_bf16(ah[bb], wl[j], acc2[bb][j], 0, 0, 0);
                    acc2[bb][j] = __builtin_amdgcn_mfma_f32_16x16x32_bf16(al[bb], wh[j], acc2[bb][j], 0, 0, 0);
                }
        }

        // ---- V = x_old - gamma*acc2 (kept in the acc registers) ----
        #pragma unroll
        for (int bb = 0; bb < 2; ++bb)
            #pragma unroll
            for (int j = 0; j < 8; ++j) {
                const int n = w * 128 + j * 16 + r16;
                #pragma unroll
                for (int r = 0; r < 4; ++r) {
                    const int b = bb * 16 + qd * 4 + r;
                    const unsigned nb2 = ((unsigned)(n * 2)) ^ ((unsigned)((b & 7) << 4));
                    float xo = bf2f(*(const unsigned short*)(lds + XH_OFF + b * 2048 + nb2)) +
                               bf2f(*(const unsigned short*)(lds + XL_OFF + b * 2048 + nb2));
                    acc2[bb][j][r] = xo - gm * acc2[bb][j][r];
                }
            }
        __syncthreads();   // all Rt reads done -> region reusable for select

        // ---- exact per-row 50th-largest |v|: 4-pass radix histogram ----
        // (bits [30:23],[22:15],[14:7],[6:0]; 256 bins packed 2 counts/u32 word)
        uint32_t* hist = (uint32_t*)(lds + RH_OFF);
        uint32_t* prefA = (uint32_t*)(lds + PREF_OFF);
        uint32_t* rkA = (uint32_t*)(lds + RK_OFF);
        #pragma unroll
        for (int i = 0; i < 9; ++i) {
            int idx = tid + i * 512;
            if (idx < 32 * HSTRIDE) hist[idx] = 0u;
        }
        if (tid < 32) { prefA[tid] = 0u; rkA[tid] = TOPK; }
        __syncthreads();

        const int srow = w * 4 + qd;   // row this quad scans
        #pragma unroll
        for (int pass = 0; pass < 4; ++pass) {
            const int s = (pass == 0) ? 23 : (pass == 1) ? 15 : (pass == 2) ? 7 : 0;
            const int sTop = (pass == 0) ? 31 : (pass == 1) ? 23 : (pass == 2) ? 15 : 7;
            const unsigned bmask = (pass == 3) ? 0x7Fu : 0xFFu;
            unsigned prefs[2][4];
            #pragma unroll
            for (int bb = 0; bb < 2; ++bb)
                #pragma unroll
                for (int r = 0; r < 4; ++r) prefs[bb][r] = prefA[bb * 16 + qd * 4 + r];
            #pragma unroll
            for (int bb = 0; bb < 2; ++bb)
                #pragma unroll
                for (int j = 0; j < 8; ++j)
                    #pragma unroll
                    for (int r = 0; r < 4; ++r) {
                        unsigned u = __float_as_uint(acc2[bb][j][r]) & 0x7FFFFFFFu;
                        if ((u >> sTop) == (prefs[bb][r] >> sTop)) {
                            unsigned bin = (u >> s) & bmask;
                            atomicAdd(&hist[(bb * 16 + qd * 4 + r) * HSTRIDE + (bin >> 1)],
                                      1u << ((bin & 1) * 16));
                        }
                    }
            __syncthreads();
            // suffix-scan 256 bins of row srow across the 16 lanes of this quad
            unsigned cnt[16];
            unsigned lsum = 0;
            #pragma unroll
            for (int i = 0; i < 8; ++i) {
                unsigned wd = hist[srow * HSTRIDE + r16 * 8 + i];
                cnt[2 * i] = wd & 0xFFFFu;
                cnt[2 * i + 1] = wd >> 16;
                lsum += cnt[2 * i] + cnt[2 * i + 1];
            }
            unsigned S = lsum;
            #pragma unroll
            for (int off = 1; off < 16; off <<= 1) {
                unsigned o = (unsigned)__shfl_down((int)S, off, 16);
                if (r16 + off < 16) S += o;
            }
            const unsigned rk = rkA[srow];
            const unsigned pOld = prefA[srow];
            unsigned run = S - lsum;   // count in strictly-higher lanes' bins
            #pragma unroll
            for (int i = 15; i >= 0; --i) {
                unsigned tot = run + cnt[i];
                if (run < rk && tot >= rk) {   // unique (lane,i) satisfies this
                    prefA[srow] = pOld | (((unsigned)(r16 * 16 + i)) << s);
                    rkA[srow] = rk - run;
                }
                run = tot;
            }
            __syncthreads();
            if (pass < 3) {
                #pragma unroll
                for (int i = 0; i < 9; ++i) {
                    int idx = tid + i * 512;
                    if (idx < 32 * HSTRIDE) hist[idx] = 0u;
                }
                __syncthreads();
            }
        }

        // ---- update: soft-threshold + exact top-k passthrough, write X LDS ----
        unsigned Ts[2][4];
        #pragma unroll
        for (int bb = 0; bb < 2; ++bb)
            #pragma unroll
            for (int r = 0; r < 4; ++r) Ts[bb][r] = prefA[bb * 16 + qd * 4 + r];
        #pragma unroll
        for (int bb = 0; bb < 2; ++bb)
            #pragma unroll
            for (int j = 0; j < 8; ++j) {
                const int n = w * 128 + j * 16 + r16;
                #pragma unroll
                for (int r = 0; r < 4; ++r) {
                    const int b = bb * 16 + qd * 4 + r;
                    const unsigned nb2 = ((unsigned)(n * 2)) ^ ((unsigned)((b & 7) << 4));
                    float xo = bf2f(*(const unsigned short*)(lds + XH_OFF + b * 2048 + nb2)) +
                               bf2f(*(const unsigned short*)(lds + XL_OFF + b * 2048 + nb2));
                    float v = acc2[bb][j][r];
                    float th = thv / (10.0f * fabsf(xo) + 1.0f);   // theta*g(|x|), EPS=0.1
                    float st = copysignf(fmaxf(fabsf(v) - th, 0.0f), v);
                    unsigned u = __float_as_uint(v) & 0x7FFFFFFFu;
                    float outv = (u > Ts[bb][r]) ? v : st;
                    unsigned short h = f2bf(outv);
                    *(unsigned short*)(lds + XH_OFF + b * 2048 + nb2) = h;
                    *(unsigned short*)(lds + XL_OFF + b * 2048 + nb2) = f2bf(outv - bf2f(h));
                    if (it == NITER - 1) out[(size_t)(gb0 + b) * NN + n] = outv;
                }
            }
        __syncthreads();   // X updated for next iteration's gemm1
    }
}

__global__ void tail_kernel(float* __restrict__ out) {
    if (threadIdx.x < 32) out[(size_t)NB * NN + threadIdx.x] = 0.0f;
}

extern "C" void kernel_launch(void* const* d_in, const int* in_sizes, int n_in,
                              void* d_out, int out_size, void* d_ws, size_t ws_size,
                              hipStream_t stream) {
    const float* y     = (const float*)d_in[0];
    const float* phi   = (const float*)d_in[1];
    const float* W     = (const float*)d_in[2];
    const float* gamma = (const float*)d_in[3];
    const float* theta = (const float*)d_in[4];
    float* out = (float*)d_out;

    char* ws = (char*)d_ws;
    size_t off = 0;
    unsigned short* Ph  = (unsigned short*)(ws + off); off += (size_t)NM * NN * 2;  // 512KB
    unsigned short* Pl  = (unsigned short*)(ws + off); off += (size_t)NM * NN * 2;
    unsigned short* Wth = (unsigned short*)(ws + off); off += (size_t)NN * NM * 2;
    unsigned short* Wtl = (unsigned short*)(ws + off); off += (size_t)NN * NM * 2;

    static int attr_done = 0;
    if (!attr_done) {
        (void)hipFuncSetAttribute(reinterpret_cast<const void*>(alista_fused),
                                  hipFuncAttributeMaxDynamicSharedMemorySize, 163840);
        attr_done = 1;
    }

    split_phi_kernel<<<(NM * NN) / 256, 256, 0, stream>>>(phi, Ph, Pl);
    transpose_split_W<<<dim3(NN / 32, NM / 32), dim3(32, 8), 0, stream>>>(W, Wth, Wtl);
    alista_fused<<<NBLKS, 512, 163840, stream>>>(Ph, Pl, Wth, Wtl, y, gamma, theta, out);
    tail_kernel<<<1, 32, 0, stream>>>(out);
}

// Round 2
// 3683.715 us; speedup vs baseline: 1.0223x; 1.0223x over previous
//
#include <hip/hip_runtime.h>
#include <cstdint>

#define NB 16384   // batch
#define NM 256     // M
#define NN 1024    // N
#define NITER 16
#define TOPK 50
#define BMROW 32               // batch rows per block
#define NBLKS (NB / BMROW)     // 512 blocks

typedef __attribute__((ext_vector_type(8))) short short8;   // 8 bf16 = 4 VGPRs
typedef __attribute__((ext_vector_type(4))) float f32x4;

__device__ inline unsigned short f2bf(float x) {            // RNE fp32 -> bf16
    unsigned u = __float_as_uint(x);
    return (unsigned short)((u + 0x7FFFu + ((u >> 16) & 1u)) >> 16);
}
__device__ inline float bf2f(unsigned short h) {
    return __uint_as_float(((unsigned)h) << 16);
}

// ------------- precompute: element-wise split of phi (NM x NN) -------------
__global__ __launch_bounds__(256) void split_phi_kernel(const float* __restrict__ phi,
                                                        unsigned short* __restrict__ h,
                                                        unsigned short* __restrict__ l) {
    int i = blockIdx.x * 256 + threadIdx.x;
    float v = phi[i];
    unsigned short hh = f2bf(v);
    h[i] = hh;
    l[i] = f2bf(v - bf2f(hh));
}

// -------- precompute: W (NM x NN) -> Wt (NN x NM) transposed + split -------
__global__ __launch_bounds__(256) void transpose_split_W(const float* __restrict__ W,
                                                         unsigned short* __restrict__ th,
                                                         unsigned short* __restrict__ tl) {
    __shared__ float tile[32][33];
    int n0 = blockIdx.x * 32;
    int m0 = blockIdx.y * 32;
    int tx = threadIdx.x;   // 0..31
    int ty = threadIdx.y;   // 0..7
    #pragma unroll
    for (int i = 0; i < 32; i += 8)
        tile[ty + i][tx] = W[(size_t)(m0 + ty + i) * NN + n0 + tx];
    __syncthreads();
    #pragma unroll
    for (int i = 0; i < 32; i += 8) {
        float v = tile[tx][ty + i];
        unsigned short hh = f2bf(v);
        size_t idx = (size_t)(n0 + ty + i) * NM + m0 + tx;
        th[idx] = hh;
        tl[idx] = f2bf(v - bf2f(hh));
    }
}

// ---------------- fully fused persistent-iteration kernel ----------------
// One block = 32 batch rows for all 16 iterations. X never touches HBM.
// LDS (163840 B total, dynamic):
//   XH [32][1024] bf16 @ 0       row stride 2048B, within-row byte ^= ((row&7)<<4)
//   XL            @ 65536
//   RH [32][256]  bf16 @ 131072  row stride 512B, same swizzle   } reused as select
//   RL            @ 147456                                        } scratch after gemm2
#define XH_OFF 0
#define XL_OFF 65536
#define RH_OFF 131072
#define RL_OFF 147456
#define HSTRIDE 132                      // words per row: 256 bins packed 2/word + pad
#define PREF_OFF (131072 + 4224 * 4)     // u32[32] running prefix of threshold bits
#define RK_OFF (PREF_OFF + 128)          // u32[32] remaining rank

// NOTE: LDS caps us at 1 block/CU (8 waves = 2/SIMD). Register budget up to
// 256 VGPR is therefore FREE; (512,1) stops the compiler spilling to chase
// a 4-wave/SIMD tier it can never reach (round-1: 1.25GB scratch writes).
__global__ __launch_bounds__(512, 1) void alista_fused(
        const unsigned short* __restrict__ Ph, const unsigned short* __restrict__ Pl,
        const unsigned short* __restrict__ Wth, const unsigned short* __restrict__ Wtl,
        const float* __restrict__ y, const float* __restrict__ gamma,
        const float* __restrict__ theta, float* __restrict__ out) {
    extern __shared__ char lds[];
    const int tid = threadIdx.x;
    const int w = tid >> 6;          // wave 0..7
    const int lane = tid & 63;
    const int qd = lane >> 4;        // quad 0..3
    const int r16 = lane & 15;
    const int gb0 = blockIdx.x * BMROW;
    const unsigned swzA = (unsigned)((r16 & 7) << 4);   // A-frag row swizzle

    // zero X (XH+XL = 131072 B)
    {
        uint32_t* p = (uint32_t*)lds;
        #pragma unroll
        for (int i = 0; i < 64; ++i) p[tid + i * 512] = 0u;
    }
    __syncthreads();

    // gemm1 B (phi rows m = w*32 + {0,16} + r16), 16B per lane per k-step
    const unsigned short* pPh0 = Ph + (size_t)(w * 32 + r16) * NN + qd * 8;
    const unsigned short* pPh1 = pPh0 + 16 * NN;
    const unsigned short* pPl0 = Pl + (size_t)(w * 32 + r16) * NN + qd * 8;
    const unsigned short* pPl1 = pPl0 + 16 * NN;
    // gemm2 B (Wt rows n = w*128 + j*16 + r16)
    const size_t wn0 = (size_t)(w * 128 + r16) * NM + qd * 8;

    // y values this lane needs are identical every iteration: hoist to regs
    float yreg[2][2][4];
    #pragma unroll
    for (int bb = 0; bb < 2; ++bb)
        #pragma unroll
        for (int m = 0; m < 2; ++m)
            #pragma unroll
            for (int r = 0; r < 4; ++r)
                yreg[bb][m][r] = y[(size_t)(gb0 + bb * 16 + qd * 4 + r) * NM +
                                   (w * 32 + m * 16 + r16)];

    for (int it = 0; it < NITER; ++it) {
        const float gm = gamma[it];
        const float thv = theta[it];

        // ---- GEMM1: Rt[b,m] = sum_n X[b,n]*phi[m,n] - y[b,m]  (K = 1024) ----
        f32x4 acc1[2][2];
        #pragma unroll
        for (int i = 0; i < 2; ++i)
            #pragma unroll
            for (int j = 0; j < 2; ++j) acc1[i][j] = (f32x4){0.f, 0.f, 0.f, 0.f};

        if (it != 0) {   // it==0: X == 0 -> Rt = -y, skip the K loop
            #pragma unroll 4
            for (int k = 0; k < 32; ++k) {
                short8 bh[2], bl[2], ah[2], al[2];
                bh[0] = *(const short8*)(pPh0 + k * 32);
                bh[1] = *(const short8*)(pPh1 + k * 32);
                bl[0] = *(const short8*)(pPl0 + k * 32);
                bl[1] = *(const short8*)(pPl1 + k * 32);
                const unsigned mo = ((unsigned)(k * 64 + qd * 16)) ^ swzA;
                ah[0] = *(const short8*)(lds + XH_OFF + r16 * 2048 + mo);
                ah[1] = *(const short8*)(lds + XH_OFF + (r16 + 16) * 2048 + mo);
                al[0] = *(const short8*)(lds + XL_OFF + r16 * 2048 + mo);
                al[1] = *(const short8*)(lds + XL_OFF + (r16 + 16) * 2048 + mo);
                #pragma unroll
                for (int bb = 0; bb < 2; ++bb)
                    #pragma unroll
                    for (int m = 0; m < 2; ++m) {
                        acc1[bb][m] = __builtin_amdgcn_mfma_f32_16x16x32_bf16(ah[bb], bh[m], acc1[bb][m], 0, 0, 0);
                        acc1[bb][m] = __builtin_amdgcn_mfma_f32_16x16x32_bf16(ah[bb], bl[m], acc1[bb][m], 0, 0, 0);
                        acc1[bb][m] = __builtin_amdgcn_mfma_f32_16x16x32_bf16(al[bb], bh[m], acc1[bb][m], 0, 0, 0);
                    }
            }
        }
        // epilogue: -y, split bf16 hi/lo, store Rt to LDS
        #pragma unroll
        for (int bb = 0; bb < 2; ++bb)
            #pragma unroll
            for (int m = 0; m < 2; ++m) {
                const int gmn = w * 32 + m * 16 + r16;
                #pragma unroll
                for (int r = 0; r < 4; ++r) {
                    const int b = bb * 16 + qd * 4 + r;
                    float v = acc1[bb][m][r] - yreg[bb][m][r];
                    unsigned short h = f2bf(v);
                    const unsigned mb = ((unsigned)(gmn * 2)) ^ ((unsigned)((b & 7) << 4));
                    *(unsigned short*)(lds + RH_OFF + b * 512 + mb) = h;
                    *(unsigned short*)(lds + RL_OFF + b * 512 + mb) = f2bf(v - bf2f(h));
                }
            }
        __syncthreads();   // Rt visible to all waves

        // ---- GEMM2: acc2[b,n] = sum_m Rt[b,m]*W[m,n]  (K = 256) ----
        f32x4 acc2[2][8];
        #pragma unroll
        for (int i = 0; i < 2; ++i)
            #pragma unroll
            for (int j = 0; j < 8; ++j) acc2[i][j] = (f32x4){0.f, 0.f, 0.f, 0.f};

        #pragma unroll 2
        for (int k = 0; k < 8; ++k) {
            const unsigned mo = ((unsigned)(k * 64 + qd * 16)) ^ swzA;
            short8 ah[2], al[2];
            ah[0] = *(const short8*)(lds + RH_OFF + r16 * 512 + mo);
            ah[1] = *(const short8*)(lds + RH_OFF + (r16 + 16) * 512 + mo);
            al[0] = *(const short8*)(lds + RL_OFF + r16 * 512 + mo);
            al[1] = *(const short8*)(lds + RL_OFF + (r16 + 16) * 512 + mo);
            // consume B in pairs: live B set = 4 short8 (16 VGPR), not 128
            #pragma unroll
            for (int jp = 0; jp < 4; ++jp) {
                const int j0 = 2 * jp, j1 = 2 * jp + 1;
                short8 wh0 = *(const short8*)(Wth + wn0 + j0 * 4096 + k * 32);
                short8 wl0 = *(const short8*)(Wtl + wn0 + j0 * 4096 + k * 32);
                short8 wh1 = *(const short8*)(Wth + wn0 + j1 * 4096 + k * 32);
                short8 wl1 = *(const short8*)(Wtl + wn0 + j1 * 4096 + k * 32);
                #pragma unroll
                for (int bb = 0; bb < 2; ++bb) {
                    acc2[bb][j0] = __builtin_amdgcn_mfma_f32_16x16x32_bf16(ah[bb], wh0, acc2[bb][j0], 0, 0, 0);
                    acc2[bb][j0] = __builtin_amdgcn_mfma_f32_16x16x32_bf16(ah[bb], wl0, acc2[bb][j0], 0, 0, 0);
                    acc2[bb][j0] = __builtin_amdgcn_mfma_f32_16x16x32_bf16(al[bb], wh0, acc2[bb][j0], 0, 0, 0);
                    acc2[bb][j1] = __builtin_amdgcn_mfma_f32_16x16x32_bf16(ah[bb], wh1, acc2[bb][j1], 0, 0, 0);
                    acc2[bb][j1] = __builtin_amdgcn_mfma_f32_16x16x32_bf16(ah[bb], wl1, acc2[bb][j1], 0, 0, 0);
                    acc2[bb][j1] = __builtin_amdgcn_mfma_f32_16x16x32_bf16(al[bb], wh1, acc2[bb][j1], 0, 0, 0);
                }
            }
        }

        // ---- V = x_old - gamma*acc2 (kept in the acc registers) ----
        #pragma unroll
        for (int bb = 0; bb < 2; ++bb)
            #pragma unroll
            for (int j = 0; j < 8; ++j) {
                const int n = w * 128 + j * 16 + r16;
                #pragma unroll
                for (int r = 0; r < 4; ++r) {
                    const int b = bb * 16 + qd * 4 + r;
                    const unsigned nb2 = ((unsigned)(n * 2)) ^ ((unsigned)((b & 7) << 4));
                    float xo = bf2f(*(const unsigned short*)(lds + XH_OFF + b * 2048 + nb2)) +
                               bf2f(*(const unsigned short*)(lds + XL_OFF + b * 2048 + nb2));
                    acc2[bb][j][r] = xo - gm * acc2[bb][j][r];
                }
            }
        __syncthreads();   // all Rt reads done -> region reusable for select

        // ---- exact per-row 50th-largest |v|: 4-pass radix histogram ----
        // (bits [30:23],[22:15],[14:7],[6:0]; 256 bins packed 2 counts/u32 word)
        uint32_t* hist = (uint32_t*)(lds + RH_OFF);
        uint32_t* prefA = (uint32_t*)(lds + PREF_OFF);
        uint32_t* rkA = (uint32_t*)(lds + RK_OFF);
        #pragma unroll
        for (int i = 0; i < 9; ++i) {
            int idx = tid + i * 512;
            if (idx < 32 * HSTRIDE) hist[idx] = 0u;
        }
        if (tid < 32) { prefA[tid] = 0u; rkA[tid] = TOPK; }
        __syncthreads();

        const int srow = w * 4 + qd;   // row this quad scans
        #pragma unroll
        for (int pass = 0; pass < 4; ++pass) {
            const int s = (pass == 0) ? 23 : (pass == 1) ? 15 : (pass == 2) ? 7 : 0;
            const int sTop = (pass == 0) ? 31 : (pass == 1) ? 23 : (pass == 2) ? 15 : 7;
            const unsigned bmask = (pass == 3) ? 0x7Fu : 0xFFu;
            unsigned prefs[2][4];
            #pragma unroll
            for (int bb = 0; bb < 2; ++bb)
                #pragma unroll
                for (int r = 0; r < 4; ++r) prefs[bb][r] = prefA[bb * 16 + qd * 4 + r];
            #pragma unroll
            for (int bb = 0; bb < 2; ++bb)
                #pragma unroll
                for (int j = 0; j < 8; ++j)
                    #pragma unroll
                    for (int r = 0; r < 4; ++r) {
                        unsigned u = __float_as_uint(acc2[bb][j][r]) & 0x7FFFFFFFu;
                        if ((u >> sTop) == (prefs[bb][r] >> sTop)) {
                            unsigned bin = (u >> s) & bmask;
                            atomicAdd(&hist[(bb * 16 + qd * 4 + r) * HSTRIDE + (bin >> 1)],
                                      1u << ((bin & 1) * 16));
                        }
                    }
            __syncthreads();
            // suffix-scan 256 bins of row srow across the 16 lanes of this quad
            unsigned cnt[16];
            unsigned lsum = 0;
            #pragma unroll
            for (int i = 0; i < 8; ++i) {
                unsigned wd = hist[srow * HSTRIDE + r16 * 8 + i];
                cnt[2 * i] = wd & 0xFFFFu;
                cnt[2 * i + 1] = wd >> 16;
                lsum += cnt[2 * i] + cnt[2 * i + 1];
            }
            unsigned S = lsum;
            #pragma unroll
            for (int off = 1; off < 16; off <<= 1) {
                unsigned o = (unsigned)__shfl_down((int)S, off, 16);
                if (r16 + off < 16) S += o;
            }
            const unsigned rk = rkA[srow];
            const unsigned pOld = prefA[srow];
            unsigned run = S - lsum;   // count in strictly-higher lanes' bins
            #pragma unroll
            for (int i = 15; i >= 0; --i) {
                unsigned tot = run + cnt[i];
                if (run < rk && tot >= rk) {   // unique (lane,i) satisfies this
                    prefA[srow] = pOld | (((unsigned)(r16 * 16 + i)) << s);
                    rkA[srow] = rk - run;
                }
                run = tot;
            }
            __syncthreads();
            if (pass < 3) {
                #pragma unroll
                for (int i = 0; i < 9; ++i) {
                    int idx = tid + i * 512;
                    if (idx < 32 * HSTRIDE) hist[idx] = 0u;
                }
                __syncthreads();
            }
        }

        // ---- update: soft-threshold + exact top-k passthrough, write X LDS ----
        unsigned Ts[2][4];
        #pragma unroll
        for (int bb = 0; bb < 2; ++bb)
            #pragma unroll
            for (int r = 0; r < 4; ++r) Ts[bb][r] = prefA[bb * 16 + qd * 4 + r];
        #pragma unroll
        for (int bb = 0; bb < 2; ++bb)
            #pragma unroll
            for (int j = 0; j < 8; ++j) {
                const int n = w * 128 + j * 16 + r16;
                #pragma unroll
                for (int r = 0; r < 4; ++r) {
                    const int b = bb * 16 + qd * 4 + r;
                    const unsigned nb2 = ((unsigned)(n * 2)) ^ ((unsigned)((b & 7) << 4));
                    float xo = bf2f(*(const unsigned short*)(lds + XH_OFF + b * 2048 + nb2)) +
                               bf2f(*(const unsigned short*)(lds + XL_OFF + b * 2048 + nb2));
                    float v = acc2[bb][j][r];
                    float th = thv / (10.0f * fabsf(xo) + 1.0f);   // theta*g(|x|), EPS=0.1
                    float st = copysignf(fmaxf(fabsf(v) - th, 0.0f), v);
                    unsigned u = __float_as_uint(v) & 0x7FFFFFFFu;
                    float outv = (u > Ts[bb][r]) ? v : st;
                    unsigned short h = f2bf(outv);
                    *(unsigned short*)(lds + XH_OFF + b * 2048 + nb2) = h;
                    *(unsigned short*)(lds + XL_OFF + b * 2048 + nb2) = f2bf(outv - bf2f(h));
                    if (it == NITER - 1) out[(size_t)(gb0 + b) * NN + n] = outv;
                }
            }
        __syncthreads();   // X updated for next iteration's gemm1
    }
}

__global__ void tail_kernel(float* __restrict__ out) {
    if (threadIdx.x < 32) out[(size_t)NB * NN + threadIdx.x] = 0.0f;
}

extern "C" void kernel_launch(void* const* d_in, const int* in_sizes, int n_in,
                              void* d_out, int out_size, void* d_ws, size_t ws_size,
                              hipStream_t stream) {
    const float* y     = (const float*)d_in[0];
    const float* phi   = (const float*)d_in[1];
    const float* W     = (const float*)d_in[2];
    const float* gamma = (const float*)d_in[3];
    const float* theta = (const float*)d_in[4];
    float* out = (float*)d_out;

    char* ws = (char*)d_ws;
    size_t off = 0;
    unsigned short* Ph  = (unsigned short*)(ws + off); off += (size_t)NM * NN * 2;  // 512KB
    unsigned short* Pl  = (unsigned short*)(ws + off); off += (size_t)NM * NN * 2;
    unsigned short* Wth = (unsigned short*)(ws + off); off += (size_t)NN * NM * 2;
    unsigned short* Wtl = (unsigned short*)(ws + off); off += (size_t)NN * NM * 2;

    static int attr_done = 0;
    if (!attr_done) {
        (void)hipFuncSetAttribute(reinterpret_cast<const void*>(alista_fused),
                                  hipFuncAttributeMaxDynamicSharedMemorySize, 163840);
        attr_done = 1;
    }

    split_phi_kernel<<<(NM * NN) / 256, 256, 0, stream>>>(phi, Ph, Pl);
    transpose_split_W<<<dim3(NN / 32, NM / 32), dim3(32, 8), 0, stream>>>(W, Wth, Wtl);
    alista_fused<<<NBLKS, 512, 163840, stream>>>(Ph, Pl, Wth, Wtl, y, gamma, theta, out);
    tail_kernel<<<1, 32, 0, stream>>>(out);
}